// Round 10
// baseline (7824.443 us; speedup 1.0000x reference)
//
#include <hip/hip_runtime.h>
#include <hip/hip_bf16.h>
#include <math.h>

#define BATCH   16
#define SEQ     768
#define DMODEL  512
#define DSTATE  128
#define DINNER  1024
#define NHEADS  16
#define HEADDIM 64
#define CONVDIM 1280            // DINNER + 2*DSTATE
#define DINPROJ 2320            // 2*DINNER + 2*DSTATE + NHEADS
#define DINPROJP 2432           // padded to multiple of 128 for GEMM tiles
#define DTBASE  2304            // DINNER + CONVDIM: dt columns start here
#define NLAYER  28
#define VOCABSZ 256
#define NROWS   (BATCH*SEQ)     // 12288
#define EPSV    1e-5f
#define NCH     8               // chunks per sequence
#define CH      96              // SEQ / NCH
#define STATESZ (HEADDIM*DSTATE) // 8192 floats per (b,h,chunk)

typedef __hip_bfloat16 bf16_t;
typedef __attribute__((ext_vector_type(8))) __bf16 bf16x8;
typedef __attribute__((ext_vector_type(4))) float floatx4;

__device__ __forceinline__ float siluf(float v) { return v / (1.f + expf(-v)); }

// async global->LDS, 16B per lane; LDS dest = wave-uniform base + lane*16
__device__ __forceinline__ void gload_lds16(const bf16_t* g, bf16_t* l) {
  __builtin_amdgcn_global_load_lds(
      (const __attribute__((address_space(1))) unsigned int*)g,
      (__attribute__((address_space(3))) unsigned int*)l, 16, 0, 0);
}

// ---------------- embed + residual zero + embedding bf16 cvt, one dispatch ----------------
__global__ __launch_bounds__(256) void embed_kernel(const int* __restrict__ tok,
    const float* __restrict__ emb, float* __restrict__ hid, float* __restrict__ res,
    bf16_t* __restrict__ w_emb_bf) {
  int i = blockIdx.x * 256 + threadIdx.x;
  const int total = NROWS * DMODEL;
  if (i < total) {
    int r = i >> 9;               // / DMODEL
    int d = i & (DMODEL - 1);
    hid[i] = emb[(size_t)tok[r] * DMODEL + d];
    res[i] = 0.f;
  } else {
    int j = i - total;
    if (j < VOCABSZ * DMODEL) w_emb_bf[j] = __float2bfloat16(emb[j]);
  }
}

// ---------------- per-layer weight conversion (fallback when ws is small) ----------------
__global__ __launch_bounds__(256) void cvt_weights_kernel(const float* __restrict__ ipw,
    const float* __restrict__ opw, bf16_t* __restrict__ win, bf16_t* __restrict__ wout) {
  int i = blockIdx.x * 256 + threadIdx.x;
  const int n1 = DINPROJP * DMODEL;
  if (i < n1) {
    int row = i >> 9, col = i & (DMODEL - 1);
    float v = (row < DINPROJ) ? ipw[(size_t)row * DMODEL + col] : 0.f;
    win[i] = __float2bfloat16(v);
  } else {
    int j = i - n1;
    if (j < DMODEL * DINNER) wout[j] = __float2bfloat16(opw[j]);
  }
}

// ---------------- ALL-layer weight conversion, one dispatch (hoisted out of loop) ----------------
__global__ __launch_bounds__(256) void cvt_weights_all_kernel(const float* __restrict__ ipw,
    const float* __restrict__ opw, bf16_t* __restrict__ win, bf16_t* __restrict__ wout) {
  size_t i = (size_t)blockIdx.x * 256 + threadIdx.x;
  const size_t n1 = (size_t)NLAYER * DINPROJP * DMODEL;
  if (i < n1) {
    int l = (int)(i / (DINPROJP * DMODEL));
    int j = (int)(i - (size_t)l * (DINPROJP * DMODEL));
    int row = j >> 9, col = j & (DMODEL - 1);
    float v = (row < DINPROJ) ? ipw[(size_t)l * DINPROJ * DMODEL + (size_t)row * DMODEL + col] : 0.f;
    win[i] = __float2bfloat16(v);
  } else {
    size_t j = i - n1;
    if (j < (size_t)NLAYER * DMODEL * DINNER) wout[j] = __float2bfloat16(opw[j]);
  }
}

// ---------------- residual add + RMSNorm (512 cols), bf16 out ----------------
__global__ __launch_bounds__(128) void prenorm_kernel(const float* __restrict__ h,
    float* __restrict__ res, const float* __restrict__ w, bf16_t* __restrict__ xn) {
  int row = blockIdx.x;
  int tid = threadIdx.x;        // 128 threads, one float4 each (512 cols)
  const float4* h4 = (const float4*)(h + (size_t)row * DMODEL);
  float4* r4 = (float4*)(res + (size_t)row * DMODEL);
  float4 v = r4[tid];
  float4 a = h4[tid];
  v.x += a.x; v.y += a.y; v.z += a.z; v.w += a.w;
  r4[tid] = v;
  float ss = v.x * v.x + v.y * v.y + v.z * v.z + v.w * v.w;
  #pragma unroll
  for (int o = 32; o > 0; o >>= 1) ss += __shfl_down(ss, o);
  __shared__ float wred[2];
  if ((tid & 63) == 0) wred[tid >> 6] = ss;
  __syncthreads();
  float tot = wred[0] + wred[1];
  float scale = rsqrtf(tot / (float)DMODEL + EPSV);
  const float4* w4 = (const float4*)w;
  float4 wv = w4[tid];
  union { bf16_t b[4]; uint2 u; } pk;
  pk.b[0] = __float2bfloat16(v.x * scale * wv.x);
  pk.b[1] = __float2bfloat16(v.y * scale * wv.y);
  pk.b[2] = __float2bfloat16(v.z * scale * wv.z);
  pk.b[3] = __float2bfloat16(v.w * scale * wv.w);
  ((uint2*)(xn + (size_t)row * DMODEL))[tid] = pk.u;
}

// ---------------- bf16 MFMA GEMM: C[M,N] = A[M,K] * B[N,K]^T ----------------
// 128xBN tile, 4 waves; staging via global_load_lds width=16.
// TO = float or bf16_t output. aux (optional): f32 copy of cols >= DTBASE (dt path).
template<int BN, typename TO>
__global__ __launch_bounds__(256) void gemm_bf16_bt(const bf16_t* __restrict__ A,
    const bf16_t* __restrict__ B, TO* __restrict__ C, float* __restrict__ aux,
    int M, int N, int K) {
  constexpr int JF = BN / 32;           // n-frags per wave
  __shared__ bf16_t As[128 * 32];
  __shared__ bf16_t Bs[BN * 32];
  int tid = threadIdx.x;
  int m0 = blockIdx.y * 128;
  int n0 = blockIdx.x * BN;
  int w = tid >> 6, lane = tid & 63;
  int wm = (w >> 1) * 64, wn = (w & 1) * (BN / 2);
  int l16 = lane & 15, lq = lane >> 4;
  floatx4 acc[4][JF];
  #pragma unroll
  for (int i = 0; i < 4; ++i)
    #pragma unroll
    for (int j = 0; j < JF; ++j)
      acc[i][j] = (floatx4){0.f, 0.f, 0.f, 0.f};
  int arow0 = tid >> 2, ak0 = (tid & 3) * 8;   // rows 0..63, k-seg 0..3
  const bf16_t* Abase = A + (size_t)m0 * K;
  const bf16_t* Bbase = B + (size_t)n0 * K;
  bf16_t* AsW = As + (w << 9);          // wave-uniform LDS bases (lane*16B appended by HW)
  bf16_t* BsW = Bs + (w << 9);
  for (int k0 = 0; k0 < K; k0 += 32) {
    __syncthreads();                    // previous iteration's LDS readers done
    gload_lds16(Abase + (size_t)arow0 * K + k0 + ak0, AsW);
    gload_lds16(Abase + (size_t)(arow0 + 64) * K + k0 + ak0, AsW + 2048);
    gload_lds16(Bbase + (size_t)arow0 * K + k0 + ak0, BsW);
    if (BN == 128)
      gload_lds16(Bbase + (size_t)(arow0 + 64) * K + k0 + ak0, BsW + 2048);
    __syncthreads();                    // drains vmcnt -> staged data visible
    bf16x8 af[4], bfr[JF];
    #pragma unroll
    for (int i = 0; i < 4; ++i)
      af[i] = *(const bf16x8*)(As + (wm + i * 16 + l16) * 32 + lq * 8);
    #pragma unroll
    for (int j = 0; j < JF; ++j)
      bfr[j] = *(const bf16x8*)(Bs + (wn + j * 16 + l16) * 32 + lq * 8);
    #pragma unroll
    for (int i = 0; i < 4; ++i)
      #pragma unroll
      for (int j = 0; j < JF; ++j)
        acc[i][j] = __builtin_amdgcn_mfma_f32_16x16x32_bf16(af[i], bfr[j], acc[i][j], 0, 0, 0);
  }
  #pragma unroll
  for (int i = 0; i < 4; ++i) {
    #pragma unroll
    for (int j = 0; j < JF; ++j) {
      int n = n0 + wn + j * 16 + l16;
      if (n < N) {
        int mb = m0 + wm + i * 16 + lq * 4;
        #pragma unroll
        for (int r = 0; r < 4; ++r) {
          float vv = acc[i][j][r];
          if constexpr (sizeof(TO) == 2)
            C[(size_t)(mb + r) * N + n] = __float2bfloat16(vv);
          else
            C[(size_t)(mb + r) * N + n] = vv;
          if (aux && n >= DTBASE)
            aux[(size_t)(mb + r) * NHEADS + (n - DTBASE)] = vv;
        }
      }
    }
  }
}

// ---------------- fused causal conv (width 4) + silu + dt/ldA ----------------
// zx stored bf16; dt columns come from f32 dtcol (precision-critical path).
__global__ __launch_bounds__(320) void convdt_kernel(const bf16_t* __restrict__ zx,
    const float* __restrict__ dtcol, const float* __restrict__ cw,
    const float* __restrict__ cb, const float* __restrict__ dt_bias,
    const float* __restrict__ A_log, bf16_t* __restrict__ out,
    float* __restrict__ dt, float* __restrict__ ldA) {
  int bl0 = blockIdx.x * 4;                    // 4 consecutive rows, same sequence (SEQ%4==0)
  int t0 = bl0 % SEQ;
  int tid = threadIdx.x;                       // 0..319
  int c = tid * 4;
  const bf16_t* base = zx + (size_t)bl0 * DINPROJ + DINNER + c;
  float4 v[7];
  #pragma unroll
  for (int k = 0; k < 7; ++k) {
    int tt = t0 + k - 3;
    if (tt >= 0) {
      union { ushort4 u; bf16_t b[4]; } q;
      q.u = *(const ushort4*)(base + (ptrdiff_t)(k - 3) * DINPROJ);
      v[k] = make_float4(__bfloat162float(q.b[0]), __bfloat162float(q.b[1]),
                         __bfloat162float(q.b[2]), __bfloat162float(q.b[3]));
    } else {
      v[k] = make_float4(0.f, 0.f, 0.f, 0.f);
    }
  }
  float4 w0 = *(const float4*)(cw + (size_t)(c + 0) * 4);
  float4 w1 = *(const float4*)(cw + (size_t)(c + 1) * 4);
  float4 w2 = *(const float4*)(cw + (size_t)(c + 2) * 4);
  float4 w3 = *(const float4*)(cw + (size_t)(c + 3) * 4);
  float4 bias = *(const float4*)(cb + c);
  const float* w0f = (const float*)&w0;
  const float* w1f = (const float*)&w1;
  const float* w2f = (const float*)&w2;
  const float* w3f = (const float*)&w3;
  #pragma unroll
  for (int j = 0; j < 4; ++j) {
    float4 acc = bias;
    #pragma unroll
    for (int k = 0; k < 4; ++k) {
      float4 vv = v[j + k];
      acc.x += vv.x * w0f[k];
      acc.y += vv.y * w1f[k];
      acc.z += vv.z * w2f[k];
      acc.w += vv.w * w3f[k];
    }
    union { ushort4 u; bf16_t b[4]; } pk;
    pk.b[0] = __float2bfloat16(siluf(acc.x));
    pk.b[1] = __float2bfloat16(siluf(acc.y));
    pk.b[2] = __float2bfloat16(siluf(acc.z));
    pk.b[3] = __float2bfloat16(siluf(acc.w));
    *(ushort4*)(out + (size_t)(bl0 + j) * CONVDIM + c) = pk.u;
  }
  if (tid < 64) {
    int j = tid >> 4, h = tid & 15;
    int bl = bl0 + j;
    float vv = dtcol[(size_t)bl * NHEADS + h] + dt_bias[h];
    float sp = fmaxf(vv, 0.f) + log1pf(expf(-fabsf(vv)));
    float Ah = -expf(A_log[h]);
    dt[bl * NHEADS + h] = sp;
    ldA[bl * NHEADS + h] = sp * Ah;            // log dA (<= 0)
  }
}

// ---------------- MFMA chunked-SSD scan: per (b, chunk, 8-head group) ----------------
// Static BT (n,t) built once/block; per-head weighted xTw carries the state weights
// (S = BT @ xTw), removing the per-head 24-iter BTw rebuild.
__global__ __launch_bounds__(512) void scan_mfma_kernel(const bf16_t* __restrict__ conv,
    const float* __restrict__ dtb, const float* __restrict__ ldAb,
    const float* __restrict__ Dp, float* __restrict__ y,
    float* __restrict__ state, float* __restrict__ chunkprod,
    float* __restrict__ cumb) {
  const int c  = blockIdx.x;                 // chunk
  const int b  = blockIdx.y >> 1;
  const int h0 = (blockIdx.y & 1) * 8;       // head group base
  const int tid  = threadIdx.x;              // 0..511
  const int w    = tid >> 6;                 // wave 0..7
  const int lane = tid & 63;
  const size_t row0 = (size_t)(b * SEQ + c * CH);

  __shared__ __align__(16) bf16_t Bb[96 * 136];    // B rows (t,n), padded
  __shared__ __align__(16) bf16_t Cb[96 * 136];    // C rows (t,n)
  __shared__ __align__(16) bf16_t Pl[96 * 104];    // P rows (t,s)
  __shared__ __align__(16) bf16_t xT[64 * 104];    // x^T (p,t)
  __shared__ __align__(16) bf16_t xTw[64 * 104];   // weighted x^T (p,t)
  __shared__ __align__(16) bf16_t BT[128 * 104];   // STATIC B^T (n,t)
  __shared__ float ldas[8][96];
  __shared__ float dts[8][96];
  __shared__ float cums[8][96];
  __shared__ float wts[8][96];

  // ---- stage B, C (bf16 direct, 16B chunks) ----
  for (int i = tid; i < 96 * 32; i += 512) {
    int t = i >> 5, g = i & 31;
    bf16x8 v = *(const bf16x8*)(conv + (row0 + t) * CONVDIM + DINNER + g * 8);
    if (g < 16) *(bf16x8*)(Bb + t * 136 + g * 8) = v;
    else        *(bf16x8*)(Cb + t * 136 + (g - 16) * 8) = v;
  }
  // ---- static BT (n,t): vector global loads + bit-move transpose stores ----
  for (int i = tid; i < 1536; i += 512) {
    int t = i >> 4, n8 = (i & 15) * 8;
    union { bf16x8 v8; unsigned short s[8]; } u;
    u.v8 = *(const bf16x8*)(conv + (row0 + t) * CONVDIM + DINNER + n8);
    #pragma unroll
    for (int r = 0; r < 8; ++r)
      ((unsigned short*)BT)[(n8 + r) * 104 + t] = u.s[r];
  }
  // ---- stage dt, ldA for 8 heads ----
  for (int i = tid; i < 768; i += 512) {
    int hh = i & 7, t = i >> 3;
    size_t gi = (row0 + t) * NHEADS + h0 + hh;
    dts[hh][t]  = dtb[gi];
    ldas[hh][t] = ldAb[gi];
  }
  __syncthreads();
  // ---- cum prefix (serial per head, 8 threads) ----
  if (tid < 8) {
    float cacc = 0.f;
    for (int t = 0; t < 96; ++t) { cacc += ldas[tid][t]; cums[tid][t] = cacc; }
  }
  __syncthreads();
  // ---- state weights + chunkprod + cum export (for ycorr) ----
  for (int i = tid; i < 768; i += 512) {
    int hh = i & 7, t = i >> 3;
    wts[hh][t] = expf(cums[hh][95] - cums[hh][t]) * dts[hh][t];
    cumb[(row0 + t) * NHEADS + h0 + hh] = cums[hh][t];
  }
  if (tid < 8)
    chunkprod[(b * NHEADS + h0 + tid) * NCH + c] = expf(cums[tid][95]);

  // ---- G = C * B^T : 36 tiles of 16x16, wave w owns tiles {w, w+8, ...} ----
  floatx4 gacc[5];
  #pragma unroll
  for (int it = 0; it < 5; ++it) gacc[it] = (floatx4){0.f, 0.f, 0.f, 0.f};
  const int l16 = lane & 15, lk = (lane >> 4) << 3;
  #pragma unroll
  for (int it = 0; it < 5; ++it) {
    int tt = w + it * 8;
    int ti = (tt < 36) ? (tt / 6) : 0;
    int si = (tt < 36) ? (tt % 6) : 0;
    #pragma unroll
    for (int ks = 0; ks < 4; ++ks) {
      bf16x8 a = *(const bf16x8*)(Cb + (ti * 16 + l16) * 136 + ks * 32 + lk);
      bf16x8 bb = *(const bf16x8*)(Bb + (si * 16 + l16) * 136 + ks * 32 + lk);
      gacc[it] = __builtin_amdgcn_mfma_f32_16x16x32_bf16(a, bb, gacc[it], 0, 0, 0);
    }
  }

  // ---- per-head: build xT/xTw, P; then PX and S MFMA ----
  for (int hh = 0; hh < 8; ++hh) {
    __syncthreads();                    // prev head's MFMA readers done
    // x^T and weighted x^T in one pass (vector loads, bit-move + weighted stores)
    for (int i = tid; i < 768; i += 512) {
      int t = i >> 3, p8 = (i & 7) * 8;
      union { bf16x8 v8; unsigned short s[8]; } u;
      u.v8 = *(const bf16x8*)(conv + (row0 + t) * CONVDIM + (h0 + hh) * HEADDIM + p8);
      float wt = wts[hh][t];
      #pragma unroll
      for (int r = 0; r < 8; ++r) {
        ((unsigned short*)xT)[(p8 + r) * 104 + t] = u.s[r];
        xTw[(p8 + r) * 104 + t] = __float2bfloat16(wt * (float)u.v8[r]);
      }
    }
    // P from G frags (wave-local registers)
    #pragma unroll
    for (int it = 0; it < 5; ++it) {
      int tt = w + it * 8;
      if (tt < 36) {
        int ti = tt / 6, si = tt % 6;
        int scol = si * 16 + l16;
        #pragma unroll
        for (int r = 0; r < 4; ++r) {
          int trow = ti * 16 + ((lane >> 4) << 2) + r;
          float pv = 0.f;
          if (scol <= trow)
            pv = expf(cums[hh][trow] - cums[hh][scol]) * dts[hh][scol] * gacc[it][r];
          Pl[trow * 104 + scol] = __float2bfloat16(pv);
        }
      }
    }
    __syncthreads();                    // builds visible
    float Dh = Dp[h0 + hh];
    // y = P @ x : 24 tiles (6 t x 4 p), 3 per wave
    #pragma unroll
    for (int it = 0; it < 3; ++it) {
      int tt = w + it * 8;
      int ti = tt >> 2, pi = tt & 3;
      floatx4 acc = (floatx4){0.f, 0.f, 0.f, 0.f};
      #pragma unroll
      for (int ks = 0; ks < 3; ++ks) {
        bf16x8 a = *(const bf16x8*)(Pl + (ti * 16 + l16) * 104 + ks * 32 + lk);
        bf16x8 bb = *(const bf16x8*)(xT + (pi * 16 + l16) * 104 + ks * 32 + lk);
        acc = __builtin_amdgcn_mfma_f32_16x16x32_bf16(a, bb, acc, 0, 0, 0);
      }
      int p = pi * 16 + l16;
      #pragma unroll
      for (int r = 0; r < 4; ++r) {
        int t = ti * 16 + ((lane >> 4) << 2) + r;
        float xg = __bfloat162float(conv[(row0 + t) * CONVDIM + (h0 + hh) * HEADDIM + p]);
        y[((row0 + t) * NHEADS + h0 + hh) * HEADDIM + p] = acc[r] + Dh * xg;
      }
    }
    // S = BT @ xTw : 32 tiles (8 n x 4 p), 4 per wave
    size_t sb = ((size_t)(b * NHEADS + h0 + hh) * NCH + c) * STATESZ;
    #pragma unroll
    for (int it = 0; it < 4; ++it) {
      int tt = w + it * 8;
      int ni = tt >> 2, pi = tt & 3;
      floatx4 acc = (floatx4){0.f, 0.f, 0.f, 0.f};
      #pragma unroll
      for (int ks = 0; ks < 3; ++ks) {
        bf16x8 a = *(const bf16x8*)(BT + (ni * 16 + l16) * 104 + ks * 32 + lk);
        bf16x8 bb = *(const bf16x8*)(xTw + (pi * 16 + l16) * 104 + ks * 32 + lk);
        acc = __builtin_amdgcn_mfma_f32_16x16x32_bf16(a, bb, acc, 0, 0, 0);
      }
      int p = pi * 16 + l16;
      #pragma unroll
      for (int r = 0; r < 4; ++r) {
        int n = ni * 16 + ((lane >> 4) << 2) + r;
        state[sb + (size_t)n * HEADDIM + p] = acc[r];
      }
    }
  }
}

// ---------------- inter-chunk recurrence: emit combined H_in as bf16 (coalesced) ----------------
// H_in[c] = P[c-1]*H_in[c-1] + S[c-1]; written ONLY as bf16 stateT (f32 state untouched,
// no writeback). ycorr consumes stateT slot c-1 (= H_in for chunk c).
__global__ __launch_bounds__(256) void state_combine_kernel(const float* __restrict__ state,
    const float* __restrict__ cprod, bf16_t* __restrict__ stateT) {
  int bh = blockIdx.y;
  int sl = blockIdx.x;            // slice 0..7 (1024 floats each)
  int tid = threadIdx.x;
  const float4* slab = (const float4*)(state + (size_t)bh * NCH * STATESZ) + sl * 256 + tid;
  bf16_t* tb = stateT + (size_t)bh * (NCH - 1) * STATESZ + (size_t)(sl * 1024 + tid * 4);
  const float* pc = cprod + bh * NCH;
  float4 H = make_float4(0.f, 0.f, 0.f, 0.f);
  for (int c = 1; c < NCH; ++c) {
    float P = pc[c - 1];
    float4 S = slab[(size_t)(c - 1) * (STATESZ / 4)];
    H.x = P * H.x + S.x; H.y = P * H.y + S.y;
    H.z = P * H.z + S.z; H.w = P * H.w + S.w;
    union { bf16_t b[4]; uint2 u; } pk;
    pk.b[0] = __float2bfloat16(H.x); pk.b[1] = __float2bfloat16(H.y);
    pk.b[2] = __float2bfloat16(H.z); pk.b[3] = __float2bfloat16(H.w);
    *(uint2*)(tb + (size_t)(c - 1) * STATESZ) = pk.u;
  }
}

// ---------------- pass 2 (MFMA): y[t] += cA[t] * (C_t . H_in)  per (chunk>=1, 8 heads) ----------------
// H comes pre-converted bf16 from state_combine; staging = 2 vector iters + bit-move transpose.
__global__ __launch_bounds__(512) void ycorr_mfma_kernel(const bf16_t* __restrict__ conv,
    const float* __restrict__ cumb, const bf16_t* __restrict__ stateT,
    float* __restrict__ y) {
  const int c  = blockIdx.x + 1;             // chunk 1..7
  const int b  = blockIdx.y >> 1;
  const int h0 = (blockIdx.y & 1) * 8;
  const int tid  = threadIdx.x;              // 0..511
  const int w    = tid >> 6;
  const int lane = tid & 63;
  const int l16 = lane & 15, lk = (lane >> 4) << 3;
  const size_t row0 = (size_t)(b * SEQ + c * CH);

  __shared__ __align__(16) bf16_t Cb[96 * 136];   // C rows (t,n)
  __shared__ __align__(16) bf16_t HT[64 * 136];   // H^T (p,n) bf16
  __shared__ float cAs[8][96];

  // stage C rows (bf16 16B chunks): 96 rows x 16 groups
  for (int i = tid; i < 96 * 16; i += 512) {
    int t = i >> 4, g = i & 15;
    bf16x8 v = *(const bf16x8*)(conv + (row0 + t) * CONVDIM + DINNER + DSTATE + g * 8);
    *(bf16x8*)(Cb + t * 136 + g * 8) = v;
  }
  // stage cA = exp(cum) for 8 heads
  for (int i = tid; i < 768; i += 512) {
    int hh = i & 7, t = i >> 3;
    cAs[hh][t] = expf(cumb[(row0 + t) * NHEADS + h0 + hh]);
  }

  for (int hh = 0; hh < 8; ++hh) {
    __syncthreads();                    // prev head's MFMA readers done (and C/cA visible)
    // H^T: vector bf16 loads from stateT [n][p], bit-move transpose to LDS [p][n]
    const bf16_t* Hs = stateT + ((size_t)(b * NHEADS + h0 + hh) * (NCH - 1) + (c - 1)) * STATESZ;
    for (int i = tid; i < 1024; i += 512) {
      int n = i >> 3, p8 = (i & 7) * 8;
      union { bf16x8 v8; unsigned short s[8]; } u;
      u.v8 = *(const bf16x8*)(Hs + (size_t)n * HEADDIM + p8);
      #pragma unroll
      for (int r = 0; r < 8; ++r)
        ((unsigned short*)HT)[(p8 + r) * 136 + n] = u.s[r];
    }
    __syncthreads();
    // y += cA * (C @ H): 24 tiles (6 t x 4 p), 3 per wave, K=128 (4 k-steps)
    #pragma unroll
    for (int it = 0; it < 3; ++it) {
      int tt = w + it * 8;
      int ti = tt >> 2, pi = tt & 3;
      floatx4 acc = (floatx4){0.f, 0.f, 0.f, 0.f};
      #pragma unroll
      for (int ks = 0; ks < 4; ++ks) {
        bf16x8 a = *(const bf16x8*)(Cb + (ti * 16 + l16) * 136 + ks * 32 + lk);
        bf16x8 bb = *(const bf16x8*)(HT + (pi * 16 + l16) * 136 + ks * 32 + lk);
        acc = __builtin_amdgcn_mfma_f32_16x16x32_bf16(a, bb, acc, 0, 0, 0);
      }
      int p = pi * 16 + l16;
      #pragma unroll
      for (int r = 0; r < 4; ++r) {
        int t = ti * 16 + ((lane >> 4) << 2) + r;
        size_t yi = ((row0 + t) * NHEADS + h0 + hh) * HEADDIM + p;
        y[yi] += cAs[hh][t] * acc[r];
      }
    }
  }
}

// ---------------- gated RMSNorm over 1024, bf16 out ----------------
__global__ __launch_bounds__(256) void gated_norm_kernel(const float* __restrict__ y,
    const bf16_t* __restrict__ zx, const float* __restrict__ gw, bf16_t* __restrict__ out) {
  int row = blockIdx.x;
  int tid = threadIdx.x;
  const float4* y4 = (const float4*)(y + (size_t)row * DINNER);
  float4 yv = y4[tid];
  union { ushort4 u; bf16_t b[4]; } zq;
  zq.u = ((const ushort4*)(zx + (size_t)row * DINPROJ))[tid];
  float4 zv = make_float4(__bfloat162float(zq.b[0]), __bfloat162float(zq.b[1]),
                          __bfloat162float(zq.b[2]), __bfloat162float(zq.b[3]));
  float4 g;
  g.x = yv.x * siluf(zv.x); g.y = yv.y * siluf(zv.y);
  g.z = yv.z * siluf(zv.z); g.w = yv.w * siluf(zv.w);
  float ss = g.x * g.x + g.y * g.y + g.z * g.z + g.w * g.w;
  #pragma unroll
  for (int o = 32; o > 0; o >>= 1) ss += __shfl_down(ss, o);
  __shared__ float red[4];
  if ((tid & 63) == 0) red[tid >> 6] = ss;
  __syncthreads();
  float tot = red[0] + red[1] + red[2] + red[3];
  float scale = rsqrtf(tot / (float)DINNER + EPSV);
  const float4* g4 = (const float4*)gw;
  float4 wv = g4[tid];
  union { bf16_t b[4]; uint2 u; } pk;
  pk.b[0] = __float2bfloat16(g.x * scale * wv.x);
  pk.b[1] = __float2bfloat16(g.y * scale * wv.y);
  pk.b[2] = __float2bfloat16(g.z * scale * wv.z);
  pk.b[3] = __float2bfloat16(g.w * scale * wv.w);
  ((uint2*)(out + (size_t)row * DINNER))[tid] = pk.u;
}

// ---------------- per-row loss: lse - logit[target] ----------------
__global__ __launch_bounds__(256) void rowloss_kernel(const float* __restrict__ logits,
    const int* __restrict__ targets, float* __restrict__ rl) {
  int row = blockIdx.x * 4 + (threadIdx.x >> 6);
  int lane = threadIdx.x & 63;
  const float* lr = logits + (size_t)row * VOCABSZ;
  float4 v = ((const float4*)lr)[lane];
  float mx = fmaxf(fmaxf(v.x, v.y), fmaxf(v.z, v.w));
  #pragma unroll
  for (int o = 32; o > 0; o >>= 1) mx = fmaxf(mx, __shfl_down(mx, o));
  mx = __shfl(mx, 0);
  float e = expf(v.x - mx) + expf(v.y - mx) + expf(v.z - mx) + expf(v.w - mx);
  #pragma unroll
  for (int o = 32; o > 0; o >>= 1) e += __shfl_down(e, o);
  if (lane == 0) {
    float lse = logf(e) + mx;
    rl[row] = lse - lr[targets[row]];
  }
}

__global__ __launch_bounds__(256) void loss_reduce_kernel(const float* __restrict__ rl,
    float* __restrict__ out) {
  int tid = threadIdx.x;
  float ssum = 0.f;
  for (int i = tid; i < NROWS; i += 256) ssum += rl[i];
  #pragma unroll
  for (int o = 32; o > 0; o >>= 1) ssum += __shfl_down(ssum, o);
  __shared__ float red[4];
  if ((tid & 63) == 0) red[tid >> 6] = ssum;
  __syncthreads();
  if (tid == 0) out[0] = (red[0] + red[1] + red[2] + red[3]) / (float)NROWS;
}

extern "C" void kernel_launch(void* const* d_in, const int* in_sizes, int n_in,
                              void* d_out, int out_size, void* d_ws, size_t ws_size,
                              hipStream_t stream) {
  const int*   tokens       = (const int*)d_in[0];
  const int*   targets      = (const int*)d_in[1];
  const float* embedding    = (const float*)d_in[2];
  const float* in_proj_w    = (const float*)d_in[3];
  const float* conv_w       = (const float*)d_in[4];
  const float* conv_b       = (const float*)d_in[5];
  const float* dt_bias      = (const float*)d_in[6];
  const float* A_log        = (const float*)d_in[7];
  const float* Dp           = (const float*)d_in[8];
  const float* gnorm_w      = (const float*)d_in[9];
  const float* out_proj_w   = (const float*)d_in[10];
  const float* block_norm_w = (const float*)d_in[11];
  const float* norm_f_w     = (const float*)d_in[12];
  float* out = (float*)d_out;

  float* ws = (float*)d_ws;
  size_t off = 0;
  float* hidden   = ws + off; off += (size_t)NROWS * DMODEL;
  float* residual = ws + off; off += (size_t)NROWS * DMODEL;
  bf16_t* zx      = (bf16_t*)(ws + off); off += (size_t)NROWS * DINPROJ / 2;
  float* dtcol    = ws + off; off += (size_t)NROWS * NHEADS;
  bf16_t* convo   = (bf16_t*)(ws + off); off += (size_t)NROWS * CONVDIM / 2;
  float* dtb      = ws + off; off += (size_t)NROWS * NHEADS;
  float* ldAb     = ws + off; off += (size_t)NROWS * NHEADS;
  float* cumbuf   = ws + off; off += (size_t)NROWS * NHEADS;
  float* ybuf     = ws + off; off += (size_t)NROWS * DINNER;
  float* cprod    = ws + off; off += (size_t)BATCH * NHEADS * NCH;
  float* rowloss  = ws + off; off += NROWS;
  bf16_t* w_emb_bf = (bf16_t*)(ws + off); off += (size_t)VOCABSZ * DMODEL / 2;
  bf16_t* stateT  = (bf16_t*)(ws + off); off += (size_t)BATCH * NHEADS * (NCH - 1) * STATESZ / 2;
  // union region: state (f32) vs bf16 activations (disjoint live ranges)
  float*  state  = ws + off;
  bf16_t* xn_bf  = (bf16_t*)(ws + off);   // live prenorm -> gemm1
  bf16_t* yn_bf  = (bf16_t*)(ws + off);   // live gated_norm -> gemm2
  off += (size_t)BATCH * NHEADS * NCH * STATESZ;
  // weight region (last): all-layer if ws allows, else per-layer reuse
  bf16_t* w_in_base = (bf16_t*)(ws + off);
  const size_t in_elems  = (size_t)DINPROJP * DMODEL;
  const size_t out_elems = (size_t)DMODEL * DINNER;
  size_t off_all = off + (size_t)NLAYER * (in_elems + out_elems) / 2;
  bool hoist = ws_size >= off_all * sizeof(float);
  bf16_t* w_out_all = w_in_base + (size_t)NLAYER * in_elems;   // hoisted layout
  bf16_t* w_out_pl  = w_in_base + in_elems;                    // per-layer layout

  embed_kernel<<<(NROWS * DMODEL + VOCABSZ * DMODEL) / 256, 256, 0, stream>>>(
      tokens, embedding, hidden, residual, w_emb_bf);

  if (hoist) {
    size_t total = (size_t)NLAYER * (in_elems + out_elems);
    cvt_weights_all_kernel<<<(unsigned)((total + 255) / 256), 256, 0, stream>>>(
        in_proj_w, out_proj_w, w_in_base, w_out_all);
  }

  const int cvt_total = DINPROJP * DMODEL + DMODEL * DINNER;
  for (int l = 0; l < NLAYER; ++l) {
    const float* ipw = in_proj_w + (size_t)l * DINPROJ * DMODEL;
    const float* cw  = conv_w + (size_t)l * CONVDIM * 4;
    const float* cb  = conv_b + (size_t)l * CONVDIM;
    const float* dtbias_l = dt_bias + (size_t)l * NHEADS;
    const float* alog_l   = A_log + (size_t)l * NHEADS;
    const float* D_l      = Dp + (size_t)l * NHEADS;
    const float* gw  = gnorm_w + (size_t)l * DINNER;
    const float* opw = out_proj_w + (size_t)l * DMODEL * DINNER;
    const float* bnw = block_norm_w + (size_t)l * DMODEL;

    const bf16_t* wi = hoist ? (w_in_base + (size_t)l * in_elems) : w_in_base;
    const bf16_t* wo = hoist ? (w_out_all + (size_t)l * out_elems) : w_out_pl;
    if (!hoist)
      cvt_weights_kernel<<<(cvt_total + 255) / 256, 256, 0, stream>>>(ipw, opw,
                                                                      w_in_base, w_out_pl);
    prenorm_kernel<<<NROWS, 128, 0, stream>>>(hidden, residual, bnw, xn_bf);
    dim3 g1(DINPROJP / 128, NROWS / 128);
    gemm_bf16_bt<128, bf16_t><<<g1, 256, 0, stream>>>(xn_bf, wi, zx, dtcol,
                                                      NROWS, DINPROJ, DMODEL);
    convdt_kernel<<<NROWS / 4, 320, 0, stream>>>(zx, dtcol, cw, cb, dtbias_l, alog_l,
                                                 convo, dtb, ldAb);
    scan_mfma_kernel<<<dim3(NCH, BATCH * 2), 512, 0, stream>>>(
        convo, dtb, ldAb, D_l, ybuf, state, cprod, cumbuf);
    state_combine_kernel<<<dim3(NCH, BATCH * NHEADS), 256, 0, stream>>>(state, cprod, stateT);
    ycorr_mfma_kernel<<<dim3(NCH - 1, BATCH * 2), 512, 0, stream>>>(
        convo, cumbuf, stateT, ybuf);
    gated_norm_kernel<<<NROWS, 256, 0, stream>>>(ybuf, zx, gw, yn_bf);
    dim3 g2(DMODEL / 64, NROWS / 128);
    gemm_bf16_bt<64, float><<<g2, 256, 0, stream>>>(yn_bf, wo, hidden, nullptr,
                                                    NROWS, DMODEL, DINNER);
  }

  prenorm_kernel<<<NROWS, 128, 0, stream>>>(hidden, residual, norm_f_w, xn_bf);
  dim3 g3(VOCABSZ / 64, NROWS / 128);
  gemm_bf16_bt<64, float><<<g3, 256, 0, stream>>>(xn_bf, w_emb_bf, out, nullptr,
                                                  NROWS, VOCABSZ, DMODEL);
  rowloss_kernel<<<NROWS / 4, 256, 0, stream>>>(out, targets, rowloss);
  loss_reduce_kernel<<<1, 256, 0, stream>>>(rowloss, out + (size_t)(out_size - 1));
}

// Round 11
// 7555.956 us; speedup vs baseline: 1.0355x; 1.0355x over previous
//
#include <hip/hip_runtime.h>
#include <hip/hip_bf16.h>
#include <math.h>

#define BATCH   16
#define SEQ     768
#define DMODEL  512
#define DSTATE  128
#define DINNER  1024
#define NHEADS  16
#define HEADDIM 64
#define CONVDIM 1280            // DINNER + 2*DSTATE
#define DINPROJ 2320            // 2*DINNER + 2*DSTATE + NHEADS
#define DINPROJP 2432           // padded to multiple of 128 for GEMM tiles
#define DTBASE  2304            // DINNER + CONVDIM: dt columns start here
#define NLAYER  28
#define VOCABSZ 256
#define NROWS   (BATCH*SEQ)     // 12288
#define EPSV    1e-5f
#define NCH     8               // chunks per sequence
#define CH      96              // SEQ / NCH
#define STATESZ (HEADDIM*DSTATE) // 8192 floats per (b,h,chunk)

typedef __hip_bfloat16 bf16_t;
typedef __attribute__((ext_vector_type(8))) __bf16 bf16x8;
typedef __attribute__((ext_vector_type(4))) float floatx4;

__device__ __forceinline__ float siluf(float v) { return v / (1.f + expf(-v)); }

// async global->LDS, 16B per lane; LDS dest = wave-uniform base + lane*16
__device__ __forceinline__ void gload_lds16(const bf16_t* g, bf16_t* l) {
  __builtin_amdgcn_global_load_lds(
      (const __attribute__((address_space(1))) unsigned int*)g,
      (__attribute__((address_space(3))) unsigned int*)l, 16, 0, 0);
}

// ---------------- embed + residual zero + embedding bf16 cvt, one dispatch ----------------
__global__ __launch_bounds__(256) void embed_kernel(const int* __restrict__ tok,
    const float* __restrict__ emb, float* __restrict__ hid, float* __restrict__ res,
    bf16_t* __restrict__ w_emb_bf) {
  int i = blockIdx.x * 256 + threadIdx.x;
  const int total = NROWS * DMODEL;
  if (i < total) {
    int r = i >> 9;               // / DMODEL
    int d = i & (DMODEL - 1);
    hid[i] = emb[(size_t)tok[r] * DMODEL + d];
    res[i] = 0.f;
  } else {
    int j = i - total;
    if (j < VOCABSZ * DMODEL) w_emb_bf[j] = __float2bfloat16(emb[j]);
  }
}

// ---------------- per-layer weight conversion (fallback when ws is small) ----------------
__global__ __launch_bounds__(256) void cvt_weights_kernel(const float* __restrict__ ipw,
    const float* __restrict__ opw, bf16_t* __restrict__ win, bf16_t* __restrict__ wout) {
  int i = blockIdx.x * 256 + threadIdx.x;
  const int n1 = DINPROJP * DMODEL;
  if (i < n1) {
    int row = i >> 9, col = i & (DMODEL - 1);
    float v = (row < DINPROJ) ? ipw[(size_t)row * DMODEL + col] : 0.f;
    win[i] = __float2bfloat16(v);
  } else {
    int j = i - n1;
    if (j < DMODEL * DINNER) wout[j] = __float2bfloat16(opw[j]);
  }
}

// ---------------- ALL-layer weight conversion, vectorized: 8 elems/thread ----------------
__global__ __launch_bounds__(256) void cvt_weights_all_kernel(const float* __restrict__ ipw,
    const float* __restrict__ opw, bf16_t* __restrict__ win, bf16_t* __restrict__ wout) {
  size_t i8 = ((size_t)blockIdx.x * 256 + threadIdx.x) * 8;
  const size_t n1 = (size_t)NLAYER * DINPROJP * DMODEL;
  union { bf16_t b[8]; uint4 u; } pk;
  if (i8 < n1) {
    int l = (int)(i8 / ((size_t)DINPROJP * DMODEL));
    int j = (int)(i8 - (size_t)l * DINPROJP * DMODEL);
    int row = j >> 9, col = j & (DMODEL - 1);     // 8 consecutive cols, same row
    if (row < DINPROJ) {
      const float* src = ipw + (size_t)l * DINPROJ * DMODEL + (size_t)row * DMODEL + col;
      float4 lo = *(const float4*)src;
      float4 hi = *(const float4*)(src + 4);
      pk.b[0] = __float2bfloat16(lo.x); pk.b[1] = __float2bfloat16(lo.y);
      pk.b[2] = __float2bfloat16(lo.z); pk.b[3] = __float2bfloat16(lo.w);
      pk.b[4] = __float2bfloat16(hi.x); pk.b[5] = __float2bfloat16(hi.y);
      pk.b[6] = __float2bfloat16(hi.z); pk.b[7] = __float2bfloat16(hi.w);
    } else {
      #pragma unroll
      for (int r = 0; r < 8; ++r) pk.b[r] = __float2bfloat16(0.f);
    }
    *(uint4*)(win + i8) = pk.u;
  } else {
    size_t j = i8 - n1;
    if (j < (size_t)NLAYER * DMODEL * DINNER) {
      float4 lo = *(const float4*)(opw + j);
      float4 hi = *(const float4*)(opw + j + 4);
      pk.b[0] = __float2bfloat16(lo.x); pk.b[1] = __float2bfloat16(lo.y);
      pk.b[2] = __float2bfloat16(lo.z); pk.b[3] = __float2bfloat16(lo.w);
      pk.b[4] = __float2bfloat16(hi.x); pk.b[5] = __float2bfloat16(hi.y);
      pk.b[6] = __float2bfloat16(hi.z); pk.b[7] = __float2bfloat16(hi.w);
      *(uint4*)(wout + j) = pk.u;
    }
  }
}

// ---------------- residual add + RMSNorm (512 cols), bf16 out ----------------
__global__ __launch_bounds__(128) void prenorm_kernel(const float* __restrict__ h,
    float* __restrict__ res, const float* __restrict__ w, bf16_t* __restrict__ xn) {
  int row = blockIdx.x;
  int tid = threadIdx.x;        // 128 threads, one float4 each (512 cols)
  const float4* h4 = (const float4*)(h + (size_t)row * DMODEL);
  float4* r4 = (float4*)(res + (size_t)row * DMODEL);
  float4 v = r4[tid];
  float4 a = h4[tid];
  v.x += a.x; v.y += a.y; v.z += a.z; v.w += a.w;
  r4[tid] = v;
  float ss = v.x * v.x + v.y * v.y + v.z * v.z + v.w * v.w;
  #pragma unroll
  for (int o = 32; o > 0; o >>= 1) ss += __shfl_down(ss, o);
  __shared__ float wred[2];
  if ((tid & 63) == 0) wred[tid >> 6] = ss;
  __syncthreads();
  float tot = wred[0] + wred[1];
  float scale = rsqrtf(tot / (float)DMODEL + EPSV);
  const float4* w4 = (const float4*)w;
  float4 wv = w4[tid];
  union { bf16_t b[4]; uint2 u; } pk;
  pk.b[0] = __float2bfloat16(v.x * scale * wv.x);
  pk.b[1] = __float2bfloat16(v.y * scale * wv.y);
  pk.b[2] = __float2bfloat16(v.z * scale * wv.z);
  pk.b[3] = __float2bfloat16(v.w * scale * wv.w);
  ((uint2*)(xn + (size_t)row * DMODEL))[tid] = pk.u;
}

// ---------------- bf16 MFMA GEMM: C[M,N] = A[M,K] * B[N,K]^T ----------------
// 128xBN tile, 4 waves; staging via global_load_lds width=16.
// TO = float or bf16_t output. aux (optional): f32 copy of cols >= DTBASE (dt path).
template<int BN, typename TO>
__global__ __launch_bounds__(256) void gemm_bf16_bt(const bf16_t* __restrict__ A,
    const bf16_t* __restrict__ B, TO* __restrict__ C, float* __restrict__ aux,
    int M, int N, int K) {
  constexpr int JF = BN / 32;           // n-frags per wave
  __shared__ bf16_t As[128 * 32];
  __shared__ bf16_t Bs[BN * 32];
  int tid = threadIdx.x;
  int m0 = blockIdx.y * 128;
  int n0 = blockIdx.x * BN;
  int w = tid >> 6, lane = tid & 63;
  int wm = (w >> 1) * 64, wn = (w & 1) * (BN / 2);
  int l16 = lane & 15, lq = lane >> 4;
  floatx4 acc[4][JF];
  #pragma unroll
  for (int i = 0; i < 4; ++i)
    #pragma unroll
    for (int j = 0; j < JF; ++j)
      acc[i][j] = (floatx4){0.f, 0.f, 0.f, 0.f};
  int arow0 = tid >> 2, ak0 = (tid & 3) * 8;   // rows 0..63, k-seg 0..3
  const bf16_t* Abase = A + (size_t)m0 * K;
  const bf16_t* Bbase = B + (size_t)n0 * K;
  bf16_t* AsW = As + (w << 9);          // wave-uniform LDS bases (lane*16B appended by HW)
  bf16_t* BsW = Bs + (w << 9);
  for (int k0 = 0; k0 < K; k0 += 32) {
    __syncthreads();                    // previous iteration's LDS readers done
    gload_lds16(Abase + (size_t)arow0 * K + k0 + ak0, AsW);
    gload_lds16(Abase + (size_t)(arow0 + 64) * K + k0 + ak0, AsW + 2048);
    gload_lds16(Bbase + (size_t)arow0 * K + k0 + ak0, BsW);
    if (BN == 128)
      gload_lds16(Bbase + (size_t)(arow0 + 64) * K + k0 + ak0, BsW + 2048);
    __syncthreads();                    // drains vmcnt -> staged data visible
    bf16x8 af[4], bfr[JF];
    #pragma unroll
    for (int i = 0; i < 4; ++i)
      af[i] = *(const bf16x8*)(As + (wm + i * 16 + l16) * 32 + lq * 8);
    #pragma unroll
    for (int j = 0; j < JF; ++j)
      bfr[j] = *(const bf16x8*)(Bs + (wn + j * 16 + l16) * 32 + lq * 8);
    #pragma unroll
    for (int i = 0; i < 4; ++i)
      #pragma unroll
      for (int j = 0; j < JF; ++j)
        acc[i][j] = __builtin_amdgcn_mfma_f32_16x16x32_bf16(af[i], bfr[j], acc[i][j], 0, 0, 0);
  }
  #pragma unroll
  for (int i = 0; i < 4; ++i) {
    #pragma unroll
    for (int j = 0; j < JF; ++j) {
      int n = n0 + wn + j * 16 + l16;
      if (n < N) {
        int mb = m0 + wm + i * 16 + lq * 4;
        #pragma unroll
        for (int r = 0; r < 4; ++r) {
          float vv = acc[i][j][r];
          if constexpr (sizeof(TO) == 2)
            C[(size_t)(mb + r) * N + n] = __float2bfloat16(vv);
          else
            C[(size_t)(mb + r) * N + n] = vv;
          if (aux && n >= DTBASE)
            aux[(size_t)(mb + r) * NHEADS + (n - DTBASE)] = vv;
        }
      }
    }
  }
}

// ---------------- fused causal conv (width 4) + silu + dt/ldA ----------------
// zx stored bf16; dt columns come from f32 dtcol (precision-critical path).
__global__ __launch_bounds__(320) void convdt_kernel(const bf16_t* __restrict__ zx,
    const float* __restrict__ dtcol, const float* __restrict__ cw,
    const float* __restrict__ cb, const float* __restrict__ dt_bias,
    const float* __restrict__ A_log, bf16_t* __restrict__ out,
    float* __restrict__ dt, float* __restrict__ ldA) {
  int bl0 = blockIdx.x * 4;                    // 4 consecutive rows, same sequence (SEQ%4==0)
  int t0 = bl0 % SEQ;
  int tid = threadIdx.x;                       // 0..319
  int c = tid * 4;
  const bf16_t* base = zx + (size_t)bl0 * DINPROJ + DINNER + c;
  float4 v[7];
  #pragma unroll
  for (int k = 0; k < 7; ++k) {
    int tt = t0 + k - 3;
    if (tt >= 0) {
      union { ushort4 u; bf16_t b[4]; } q;
      q.u = *(const ushort4*)(base + (ptrdiff_t)(k - 3) * DINPROJ);
      v[k] = make_float4(__bfloat162float(q.b[0]), __bfloat162float(q.b[1]),
                         __bfloat162float(q.b[2]), __bfloat162float(q.b[3]));
    } else {
      v[k] = make_float4(0.f, 0.f, 0.f, 0.f);
    }
  }
  float4 w0 = *(const float4*)(cw + (size_t)(c + 0) * 4);
  float4 w1 = *(const float4*)(cw + (size_t)(c + 1) * 4);
  float4 w2 = *(const float4*)(cw + (size_t)(c + 2) * 4);
  float4 w3 = *(const float4*)(cw + (size_t)(c + 3) * 4);
  float4 bias = *(const float4*)(cb + c);
  const float* w0f = (const float*)&w0;
  const float* w1f = (const float*)&w1;
  const float* w2f = (const float*)&w2;
  const float* w3f = (const float*)&w3;
  #pragma unroll
  for (int j = 0; j < 4; ++j) {
    float4 acc = bias;
    #pragma unroll
    for (int k = 0; k < 4; ++k) {
      float4 vv = v[j + k];
      acc.x += vv.x * w0f[k];
      acc.y += vv.y * w1f[k];
      acc.z += vv.z * w2f[k];
      acc.w += vv.w * w3f[k];
    }
    union { ushort4 u; bf16_t b[4]; } pk;
    pk.b[0] = __float2bfloat16(siluf(acc.x));
    pk.b[1] = __float2bfloat16(siluf(acc.y));
    pk.b[2] = __float2bfloat16(siluf(acc.z));
    pk.b[3] = __float2bfloat16(siluf(acc.w));
    *(ushort4*)(out + (size_t)(bl0 + j) * CONVDIM + c) = pk.u;
  }
  if (tid < 64) {
    int j = tid >> 4, h = tid & 15;
    int bl = bl0 + j;
    float vv = dtcol[(size_t)bl * NHEADS + h] + dt_bias[h];
    float sp = fmaxf(vv, 0.f) + log1pf(expf(-fabsf(vv)));
    float Ah = -expf(A_log[h]);
    dt[bl * NHEADS + h] = sp;
    ldA[bl * NHEADS + h] = sp * Ah;            // log dA (<= 0)
  }
}

// ---------------- MFMA chunked-SSD scan: per (b, chunk, 8-head group) ----------------
// Static BT (n,t) built once/block; per-head weighted xTw carries the state weights
// (S = BT @ xTw). y output stored bf16.
__global__ __launch_bounds__(512) void scan_mfma_kernel(const bf16_t* __restrict__ conv,
    const float* __restrict__ dtb, const float* __restrict__ ldAb,
    const float* __restrict__ Dp, bf16_t* __restrict__ y,
    float* __restrict__ state, float* __restrict__ chunkprod,
    float* __restrict__ cumb) {
  const int c  = blockIdx.x;                 // chunk
  const int b  = blockIdx.y >> 1;
  const int h0 = (blockIdx.y & 1) * 8;       // head group base
  const int tid  = threadIdx.x;              // 0..511
  const int w    = tid >> 6;                 // wave 0..7
  const int lane = tid & 63;
  const size_t row0 = (size_t)(b * SEQ + c * CH);

  __shared__ __align__(16) bf16_t Bb[96 * 136];    // B rows (t,n), padded
  __shared__ __align__(16) bf16_t Cb[96 * 136];    // C rows (t,n)
  __shared__ __align__(16) bf16_t Pl[96 * 104];    // P rows (t,s)
  __shared__ __align__(16) bf16_t xT[64 * 104];    // x^T (p,t)
  __shared__ __align__(16) bf16_t xTw[64 * 104];   // weighted x^T (p,t)
  __shared__ __align__(16) bf16_t BT[128 * 104];   // STATIC B^T (n,t)
  __shared__ float ldas[8][96];
  __shared__ float dts[8][96];
  __shared__ float cums[8][96];
  __shared__ float wts[8][96];

  // ---- stage B, C (bf16 direct, 16B chunks) ----
  for (int i = tid; i < 96 * 32; i += 512) {
    int t = i >> 5, g = i & 31;
    bf16x8 v = *(const bf16x8*)(conv + (row0 + t) * CONVDIM + DINNER + g * 8);
    if (g < 16) *(bf16x8*)(Bb + t * 136 + g * 8) = v;
    else        *(bf16x8*)(Cb + t * 136 + (g - 16) * 8) = v;
  }
  // ---- static BT (n,t): vector global loads + bit-move transpose stores ----
  for (int i = tid; i < 1536; i += 512) {
    int t = i >> 4, n8 = (i & 15) * 8;
    union { bf16x8 v8; unsigned short s[8]; } u;
    u.v8 = *(const bf16x8*)(conv + (row0 + t) * CONVDIM + DINNER + n8);
    #pragma unroll
    for (int r = 0; r < 8; ++r)
      ((unsigned short*)BT)[(n8 + r) * 104 + t] = u.s[r];
  }
  // ---- stage dt, ldA for 8 heads ----
  for (int i = tid; i < 768; i += 512) {
    int hh = i & 7, t = i >> 3;
    size_t gi = (row0 + t) * NHEADS + h0 + hh;
    dts[hh][t]  = dtb[gi];
    ldas[hh][t] = ldAb[gi];
  }
  __syncthreads();
  // ---- cum prefix (serial per head, 8 threads) ----
  if (tid < 8) {
    float cacc = 0.f;
    for (int t = 0; t < 96; ++t) { cacc += ldas[tid][t]; cums[tid][t] = cacc; }
  }
  __syncthreads();
  // ---- state weights + chunkprod + cum export (for ycorr) ----
  for (int i = tid; i < 768; i += 512) {
    int hh = i & 7, t = i >> 3;
    wts[hh][t] = expf(cums[hh][95] - cums[hh][t]) * dts[hh][t];
    cumb[(row0 + t) * NHEADS + h0 + hh] = cums[hh][t];
  }
  if (tid < 8)
    chunkprod[(b * NHEADS + h0 + tid) * NCH + c] = expf(cums[tid][95]);

  // ---- G = C * B^T : 36 tiles of 16x16, wave w owns tiles {w, w+8, ...} ----
  floatx4 gacc[5];
  #pragma unroll
  for (int it = 0; it < 5; ++it) gacc[it] = (floatx4){0.f, 0.f, 0.f, 0.f};
  const int l16 = lane & 15, lk = (lane >> 4) << 3;
  #pragma unroll
  for (int it = 0; it < 5; ++it) {
    int tt = w + it * 8;
    int ti = (tt < 36) ? (tt / 6) : 0;
    int si = (tt < 36) ? (tt % 6) : 0;
    #pragma unroll
    for (int ks = 0; ks < 4; ++ks) {
      bf16x8 a = *(const bf16x8*)(Cb + (ti * 16 + l16) * 136 + ks * 32 + lk);
      bf16x8 bb = *(const bf16x8*)(Bb + (si * 16 + l16) * 136 + ks * 32 + lk);
      gacc[it] = __builtin_amdgcn_mfma_f32_16x16x32_bf16(a, bb, gacc[it], 0, 0, 0);
    }
  }

  // ---- per-head: build xT/xTw, P; then PX and S MFMA ----
  for (int hh = 0; hh < 8; ++hh) {
    __syncthreads();                    // prev head's MFMA readers done
    // x^T and weighted x^T in one pass (vector loads, bit-move + weighted stores)
    for (int i = tid; i < 768; i += 512) {
      int t = i >> 3, p8 = (i & 7) * 8;
      union { bf16x8 v8; unsigned short s[8]; } u;
      u.v8 = *(const bf16x8*)(conv + (row0 + t) * CONVDIM + (h0 + hh) * HEADDIM + p8);
      float wt = wts[hh][t];
      #pragma unroll
      for (int r = 0; r < 8; ++r) {
        ((unsigned short*)xT)[(p8 + r) * 104 + t] = u.s[r];
        xTw[(p8 + r) * 104 + t] = __float2bfloat16(wt * (float)u.v8[r]);
      }
    }
    // P from G frags (wave-local registers)
    #pragma unroll
    for (int it = 0; it < 5; ++it) {
      int tt = w + it * 8;
      if (tt < 36) {
        int ti = tt / 6, si = tt % 6;
        int scol = si * 16 + l16;
        #pragma unroll
        for (int r = 0; r < 4; ++r) {
          int trow = ti * 16 + ((lane >> 4) << 2) + r;
          float pv = 0.f;
          if (scol <= trow)
            pv = expf(cums[hh][trow] - cums[hh][scol]) * dts[hh][scol] * gacc[it][r];
          Pl[trow * 104 + scol] = __float2bfloat16(pv);
        }
      }
    }
    __syncthreads();                    // builds visible
    float Dh = Dp[h0 + hh];
    // y = P @ x : 24 tiles (6 t x 4 p), 3 per wave
    #pragma unroll
    for (int it = 0; it < 3; ++it) {
      int tt = w + it * 8;
      int ti = tt >> 2, pi = tt & 3;
      floatx4 acc = (floatx4){0.f, 0.f, 0.f, 0.f};
      #pragma unroll
      for (int ks = 0; ks < 3; ++ks) {
        bf16x8 a = *(const bf16x8*)(Pl + (ti * 16 + l16) * 104 + ks * 32 + lk);
        bf16x8 bb = *(const bf16x8*)(xT + (pi * 16 + l16) * 104 + ks * 32 + lk);
        acc = __builtin_amdgcn_mfma_f32_16x16x32_bf16(a, bb, acc, 0, 0, 0);
      }
      int p = pi * 16 + l16;
      #pragma unroll
      for (int r = 0; r < 4; ++r) {
        int t = ti * 16 + ((lane >> 4) << 2) + r;
        float xg = __bfloat162float(conv[(row0 + t) * CONVDIM + (h0 + hh) * HEADDIM + p]);
        y[((row0 + t) * NHEADS + h0 + hh) * HEADDIM + p] = __float2bfloat16(acc[r] + Dh * xg);
      }
    }
    // S = BT @ xTw : 32 tiles (8 n x 4 p), 4 per wave
    size_t sb = ((size_t)(b * NHEADS + h0 + hh) * NCH + c) * STATESZ;
    #pragma unroll
    for (int it = 0; it < 4; ++it) {
      int tt = w + it * 8;
      int ni = tt >> 2, pi = tt & 3;
      floatx4 acc = (floatx4){0.f, 0.f, 0.f, 0.f};
      #pragma unroll
      for (int ks = 0; ks < 3; ++ks) {
        bf16x8 a = *(const bf16x8*)(BT + (ni * 16 + l16) * 104 + ks * 32 + lk);
        bf16x8 bb = *(const bf16x8*)(xTw + (pi * 16 + l16) * 104 + ks * 32 + lk);
        acc = __builtin_amdgcn_mfma_f32_16x16x32_bf16(a, bb, acc, 0, 0, 0);
      }
      int p = pi * 16 + l16;
      #pragma unroll
      for (int r = 0; r < 4; ++r) {
        int n = ni * 16 + ((lane >> 4) << 2) + r;
        state[sb + (size_t)n * HEADDIM + p] = acc[r];
      }
    }
  }
}

// ---------------- inter-chunk recurrence: emit combined H_in as bf16 (coalesced) ----------------
__global__ __launch_bounds__(256) void state_combine_kernel(const float* __restrict__ state,
    const float* __restrict__ cprod, bf16_t* __restrict__ stateT) {
  int bh = blockIdx.y;
  int sl = blockIdx.x;            // slice 0..7 (1024 floats each)
  int tid = threadIdx.x;
  const float4* slab = (const float4*)(state + (size_t)bh * NCH * STATESZ) + sl * 256 + tid;
  bf16_t* tb = stateT + (size_t)bh * (NCH - 1) * STATESZ + (size_t)(sl * 1024 + tid * 4);
  const float* pc = cprod + bh * NCH;
  float4 H = make_float4(0.f, 0.f, 0.f, 0.f);
  for (int c = 1; c < NCH; ++c) {
    float P = pc[c - 1];
    float4 S = slab[(size_t)(c - 1) * (STATESZ / 4)];
    H.x = P * H.x + S.x; H.y = P * H.y + S.y;
    H.z = P * H.z + S.z; H.w = P * H.w + S.w;
    union { bf16_t b[4]; uint2 u; } pk;
    pk.b[0] = __float2bfloat16(H.x); pk.b[1] = __float2bfloat16(H.y);
    pk.b[2] = __float2bfloat16(H.z); pk.b[3] = __float2bfloat16(H.w);
    *(uint2*)(tb + (size_t)(c - 1) * STATESZ) = pk.u;
  }
}

// ---------------- pass 2 (MFMA): y[t] += cA[t] * (C_t . H_in)  per (chunk>=1, 8 heads) ----------------
__global__ __launch_bounds__(512) void ycorr_mfma_kernel(const bf16_t* __restrict__ conv,
    const float* __restrict__ cumb, const bf16_t* __restrict__ stateT,
    bf16_t* __restrict__ y) {
  const int c  = blockIdx.x + 1;             // chunk 1..7
  const int b  = blockIdx.y >> 1;
  const int h0 = (blockIdx.y & 1) * 8;
  const int tid  = threadIdx.x;              // 0..511
  const int w    = tid >> 6;
  const int lane = tid & 63;
  const int l16 = lane & 15, lk = (lane >> 4) << 3;
  const size_t row0 = (size_t)(b * SEQ + c * CH);

  __shared__ __align__(16) bf16_t Cb[96 * 136];   // C rows (t,n)
  __shared__ __align__(16) bf16_t HT[64 * 136];   // H^T (p,n) bf16
  __shared__ float cAs[8][96];

  // stage C rows (bf16 16B chunks): 96 rows x 16 groups
  for (int i = tid; i < 96 * 16; i += 512) {
    int t = i >> 4, g = i & 15;
    bf16x8 v = *(const bf16x8*)(conv + (row0 + t) * CONVDIM + DINNER + DSTATE + g * 8);
    *(bf16x8*)(Cb + t * 136 + g * 8) = v;
  }
  // stage cA = exp(cum) for 8 heads
  for (int i = tid; i < 768; i += 512) {
    int hh = i & 7, t = i >> 3;
    cAs[hh][t] = expf(cumb[(row0 + t) * NHEADS + h0 + hh]);
  }

  for (int hh = 0; hh < 8; ++hh) {
    __syncthreads();                    // prev head's MFMA readers done (and C/cA visible)
    // H^T: vector bf16 loads from stateT [n][p], bit-move transpose to LDS [p][n]
    const bf16_t* Hs = stateT + ((size_t)(b * NHEADS + h0 + hh) * (NCH - 1) + (c - 1)) * STATESZ;
    for (int i = tid; i < 1024; i += 512) {
      int n = i >> 3, p8 = (i & 7) * 8;
      union { bf16x8 v8; unsigned short s[8]; } u;
      u.v8 = *(const bf16x8*)(Hs + (size_t)n * HEADDIM + p8);
      #pragma unroll
      for (int r = 0; r < 8; ++r)
        ((unsigned short*)HT)[(p8 + r) * 136 + n] = u.s[r];
    }
    __syncthreads();
    // y += cA * (C @ H): 24 tiles (6 t x 4 p), 3 per wave, K=128 (4 k-steps)
    #pragma unroll
    for (int it = 0; it < 3; ++it) {
      int tt = w + it * 8;
      int ti = tt >> 2, pi = tt & 3;
      floatx4 acc = (floatx4){0.f, 0.f, 0.f, 0.f};
      #pragma unroll
      for (int ks = 0; ks < 4; ++ks) {
        bf16x8 a = *(const bf16x8*)(Cb + (ti * 16 + l16) * 136 + ks * 32 + lk);
        bf16x8 bb = *(const bf16x8*)(HT + (pi * 16 + l16) * 136 + ks * 32 + lk);
        acc = __builtin_amdgcn_mfma_f32_16x16x32_bf16(a, bb, acc, 0, 0, 0);
      }
      int p = pi * 16 + l16;
      #pragma unroll
      for (int r = 0; r < 4; ++r) {
        int t = ti * 16 + ((lane >> 4) << 2) + r;
        size_t yi = ((row0 + t) * NHEADS + h0 + hh) * HEADDIM + p;
        y[yi] = __float2bfloat16(__bfloat162float(y[yi]) + cAs[hh][t] * acc[r]);
      }
    }
  }
}

// ---------------- gated RMSNorm over 1024 (bf16 y in), bf16 out ----------------
__global__ __launch_bounds__(256) void gated_norm_kernel(const bf16_t* __restrict__ y,
    const bf16_t* __restrict__ zx, const float* __restrict__ gw, bf16_t* __restrict__ out) {
  int row = blockIdx.x;
  int tid = threadIdx.x;
  union { ushort4 u; bf16_t b[4]; } yq;
  yq.u = ((const ushort4*)(y + (size_t)row * DINNER))[tid];
  float4 yv = make_float4(__bfloat162float(yq.b[0]), __bfloat162float(yq.b[1]),
                          __bfloat162float(yq.b[2]), __bfloat162float(yq.b[3]));
  union { ushort4 u; bf16_t b[4]; } zq;
  zq.u = ((const ushort4*)(zx + (size_t)row * DINPROJ))[tid];
  float4 zv = make_float4(__bfloat162float(zq.b[0]), __bfloat162float(zq.b[1]),
                          __bfloat162float(zq.b[2]), __bfloat162float(zq.b[3]));
  float4 g;
  g.x = yv.x * siluf(zv.x); g.y = yv.y * siluf(zv.y);
  g.z = yv.z * siluf(zv.z); g.w = yv.w * siluf(zv.w);
  float ss = g.x * g.x + g.y * g.y + g.z * g.z + g.w * g.w;
  #pragma unroll
  for (int o = 32; o > 0; o >>= 1) ss += __shfl_down(ss, o);
  __shared__ float red[4];
  if ((tid & 63) == 0) red[tid >> 6] = ss;
  __syncthreads();
  float tot = red[0] + red[1] + red[2] + red[3];
  float scale = rsqrtf(tot / (float)DINNER + EPSV);
  const float4* g4 = (const float4*)gw;
  float4 wv = g4[tid];
  union { bf16_t b[4]; uint2 u; } pk;
  pk.b[0] = __float2bfloat16(g.x * scale * wv.x);
  pk.b[1] = __float2bfloat16(g.y * scale * wv.y);
  pk.b[2] = __float2bfloat16(g.z * scale * wv.z);
  pk.b[3] = __float2bfloat16(g.w * scale * wv.w);
  ((uint2*)(out + (size_t)row * DINNER))[tid] = pk.u;
}

// ---------------- per-row loss: lse - logit[target] ----------------
__global__ __launch_bounds__(256) void rowloss_kernel(const float* __restrict__ logits,
    const int* __restrict__ targets, float* __restrict__ rl) {
  int row = blockIdx.x * 4 + (threadIdx.x >> 6);
  int lane = threadIdx.x & 63;
  const float* lr = logits + (size_t)row * VOCABSZ;
  float4 v = ((const float4*)lr)[lane];
  float mx = fmaxf(fmaxf(v.x, v.y), fmaxf(v.z, v.w));
  #pragma unroll
  for (int o = 32; o > 0; o >>= 1) mx = fmaxf(mx, __shfl_down(mx, o));
  mx = __shfl(mx, 0);
  float e = expf(v.x - mx) + expf(v.y - mx) + expf(v.z - mx) + expf(v.w - mx);
  #pragma unroll
  for (int o = 32; o > 0; o >>= 1) e += __shfl_down(e, o);
  if (lane == 0) {
    float lse = logf(e) + mx;
    rl[row] = lse - lr[targets[row]];
  }
}

__global__ __launch_bounds__(256) void loss_reduce_kernel(const float* __restrict__ rl,
    float* __restrict__ out) {
  int tid = threadIdx.x;
  float ssum = 0.f;
  for (int i = tid; i < NROWS; i += 256) ssum += rl[i];
  #pragma unroll
  for (int o = 32; o > 0; o >>= 1) ssum += __shfl_down(ssum, o);
  __shared__ float red[4];
  if ((tid & 63) == 0) red[tid >> 6] = ssum;
  __syncthreads();
  if (tid == 0) out[0] = (red[0] + red[1] + red[2] + red[3]) / (float)NROWS;
}

extern "C" void kernel_launch(void* const* d_in, const int* in_sizes, int n_in,
                              void* d_out, int out_size, void* d_ws, size_t ws_size,
                              hipStream_t stream) {
  const int*   tokens       = (const int*)d_in[0];
  const int*   targets      = (const int*)d_in[1];
  const float* embedding    = (const float*)d_in[2];
  const float* in_proj_w    = (const float*)d_in[3];
  const float* conv_w       = (const float*)d_in[4];
  const float* conv_b       = (const float*)d_in[5];
  const float* dt_bias      = (const float*)d_in[6];
  const float* A_log        = (const float*)d_in[7];
  const float* Dp           = (const float*)d_in[8];
  const float* gnorm_w      = (const float*)d_in[9];
  const float* out_proj_w   = (const float*)d_in[10];
  const float* block_norm_w = (const float*)d_in[11];
  const float* norm_f_w     = (const float*)d_in[12];
  float* out = (float*)d_out;

  float* ws = (float*)d_ws;
  size_t off = 0;
  float* hidden   = ws + off; off += (size_t)NROWS * DMODEL;
  float* residual = ws + off; off += (size_t)NROWS * DMODEL;
  bf16_t* zx      = (bf16_t*)(ws + off); off += (size_t)NROWS * DINPROJ / 2;
  float* dtcol    = ws + off; off += (size_t)NROWS * NHEADS;
  bf16_t* convo   = (bf16_t*)(ws + off); off += (size_t)NROWS * CONVDIM / 2;
  float* dtb      = ws + off; off += (size_t)NROWS * NHEADS;
  float* ldAb     = ws + off; off += (size_t)NROWS * NHEADS;
  float* cumbuf   = ws + off; off += (size_t)NROWS * NHEADS;
  bf16_t* ybuf    = (bf16_t*)(ws + off); off += (size_t)NROWS * DINNER / 2;
  float* cprod    = ws + off; off += (size_t)BATCH * NHEADS * NCH;
  float* rowloss  = ws + off; off += NROWS;
  bf16_t* w_emb_bf = (bf16_t*)(ws + off); off += (size_t)VOCABSZ * DMODEL / 2;
  bf16_t* stateT  = (bf16_t*)(ws + off); off += (size_t)BATCH * NHEADS * (NCH - 1) * STATESZ / 2;
  // union region: state (f32) vs bf16 activations (disjoint live ranges)
  float*  state  = ws + off;
  bf16_t* xn_bf  = (bf16_t*)(ws + off);   // live prenorm -> gemm1
  bf16_t* yn_bf  = (bf16_t*)(ws + off);   // live gated_norm -> gemm2
  off += (size_t)BATCH * NHEADS * NCH * STATESZ;
  // weight region (last): all-layer if ws allows, else per-layer reuse
  bf16_t* w_in_base = (bf16_t*)(ws + off);
  const size_t in_elems  = (size_t)DINPROJP * DMODEL;
  const size_t out_elems = (size_t)DMODEL * DINNER;
  size_t off_all = off + (size_t)NLAYER * (in_elems + out_elems) / 2;
  bool hoist = ws_size >= off_all * sizeof(float);
  bf16_t* w_out_all = w_in_base + (size_t)NLAYER * in_elems;   // hoisted layout
  bf16_t* w_out_pl  = w_in_base + in_elems;                    // per-layer layout

  embed_kernel<<<(NROWS * DMODEL + VOCABSZ * DMODEL) / 256, 256, 0, stream>>>(
      tokens, embedding, hidden, residual, w_emb_bf);

  if (hoist) {
    size_t total = (size_t)NLAYER * (in_elems + out_elems);
    cvt_weights_all_kernel<<<(unsigned)(total / 8 / 256), 256, 0, stream>>>(
        in_proj_w, out_proj_w, w_in_base, w_out_all);
  }

  const int cvt_total = DINPROJP * DMODEL + DMODEL * DINNER;
  for (int l = 0; l < NLAYER; ++l) {
    const float* ipw = in_proj_w + (size_t)l * DINPROJ * DMODEL;
    const float* cw  = conv_w + (size_t)l * CONVDIM * 4;
    const float* cb  = conv_b + (size_t)l * CONVDIM;
    const float* dtbias_l = dt_bias + (size_t)l * NHEADS;
    const float* alog_l   = A_log + (size_t)l * NHEADS;
    const float* D_l      = Dp + (size_t)l * NHEADS;
    const float* gw  = gnorm_w + (size_t)l * DINNER;
    const float* opw = out_proj_w + (size_t)l * DMODEL * DINNER;
    const float* bnw = block_norm_w + (size_t)l * DMODEL;

    const bf16_t* wi = hoist ? (w_in_base + (size_t)l * in_elems) : w_in_base;
    const bf16_t* wo = hoist ? (w_out_all + (size_t)l * out_elems) : w_out_pl;
    if (!hoist)
      cvt_weights_kernel<<<(cvt_total + 255) / 256, 256, 0, stream>>>(ipw, opw,
                                                                      w_in_base, w_out_pl);
    prenorm_kernel<<<NROWS, 128, 0, stream>>>(hidden, residual, bnw, xn_bf);
    dim3 g1(DINPROJP / 128, NROWS / 128);
    gemm_bf16_bt<128, bf16_t><<<g1, 256, 0, stream>>>(xn_bf, wi, zx, dtcol,
                                                      NROWS, DINPROJ, DMODEL);
    convdt_kernel<<<NROWS / 4, 320, 0, stream>>>(zx, dtcol, cw, cb, dtbias_l, alog_l,
                                                 convo, dtb, ldAb);
    scan_mfma_kernel<<<dim3(NCH, BATCH * 2), 512, 0, stream>>>(
        convo, dtb, ldAb, D_l, ybuf, state, cprod, cumbuf);
    state_combine_kernel<<<dim3(NCH, BATCH * NHEADS), 256, 0, stream>>>(state, cprod, stateT);
    ycorr_mfma_kernel<<<dim3(NCH - 1, BATCH * 2), 512, 0, stream>>>(
        convo, cumbuf, stateT, ybuf);
    gated_norm_kernel<<<NROWS, 256, 0, stream>>>(ybuf, zx, gw, yn_bf);
    dim3 g2(DMODEL / 64, NROWS / 128);
    gemm_bf16_bt<64, float><<<g2, 256, 0, stream>>>(yn_bf, wo, hidden, nullptr,
                                                    NROWS, DMODEL, DINNER);
  }

  prenorm_kernel<<<NROWS, 128, 0, stream>>>(hidden, residual, norm_f_w, xn_bf);
  dim3 g3(VOCABSZ / 64, NROWS / 128);
  gemm_bf16_bt<64, float><<<g3, 256, 0, stream>>>(xn_bf, w_emb_bf, out, nullptr,
                                                  NROWS, VOCABSZ, DMODEL);
  rowloss_kernel<<<NROWS / 4, 256, 0, stream>>>(out, targets, rowloss);
  loss_reduce_kernel<<<1, 256, 0, stream>>>(rowloss, out + (size_t)(out_size - 1));
}